// Round 5
// baseline (1012.054 us; speedup 1.0000x reference)
//
#include <hip/hip_runtime.h>

// NetG: seq2seq GRU (enc GRU -> +noise -> dec GRU -> FC head)
// B=512, T=256, H=256, D=3.
//
// Persistent-RNN: 32 blocks x 512 threads (8 waves, 2/SIMD -> 256 unified
// regs/wave). Each block owns 16 batch rows for all 256 steps.
//
// R4 post-mortem: step = 4100 cyc = MFMA pipe 1790 (43%) + ds pipe 2390
// (58%), non-overlapping. ds was dominated by streaming gate-r A-frags from
// LDS (131 KB/step). This round: ALL THREE gates' W_hh bf16 A-frags live in
// 192 regs/lane (MFMA-A-only -> AGPR-eligible). Reg diet to make it fit:
//  - x-step uses K=16 MFMA (A = 2 regs): ax 16 regs (K=32 fallback if the
//    builtin is missing).
//  - no fp32 h carry: epilogue re-reads its own bf16 h (b64) from the LDS
//    read buffer (h is bf16-carried; threshold has 5x margin).
//  - acc init via MFMA C = inline 0 (x-step issues first for each acc).
//  - X staged once in LDS [t][c] (shift baked in): per-step bx is ONE
//    ds_read_b64, no VALU build, no global loads in the loop.
// h LDS layout in FRAGMENT ORDER: element h[c][32k+q*8+j] at
// ((k*4+q)*16+c)*16B + j*2B -> B-frag read = lane base + k*1024 (immediate),
// <=2-way bank aliasing (free). Epilogue writes b64 at a fixed offset.

#define B_TOT 512
#define T_LEN 256
#define HID 256
#define NBATCH 16
#define NTHREADS 512
#define NBLK 32

#define XT 64                  // shorts per t-slot of staged X (16 c x 4)
#define XSLOTS (T_LEN + 1)     // slot t = x for step t; +1 pad slot
#define HBUF (NBATCH * HID)    // 4096 shorts per h buffer

typedef __attribute__((ext_vector_type(4))) float f32x4;
typedef __attribute__((ext_vector_type(8))) short shortx8;
typedef __attribute__((ext_vector_type(4))) short i16x4;
typedef __attribute__((ext_vector_type(4))) unsigned short ushortx4;
typedef __attribute__((ext_vector_type(8))) unsigned short ushortx8;

#if __has_builtin(__builtin_amdgcn_mfma_f32_16x16x16_bf16)
#define HAVE_K16 1
#define MFMA_X(A, B, C) __builtin_amdgcn_mfma_f32_16x16x16_bf16((A), (B), (C), 0, 0, 0)
#elif __has_builtin(__builtin_amdgcn_mfma_f32_16x16x16bf16_1k)
#define HAVE_K16 1
#define MFMA_X(A, B, C) __builtin_amdgcn_mfma_f32_16x16x16bf16_1k((A), (B), (C), 0, 0, 0)
#else
#define HAVE_K16 0
#endif

__device__ __forceinline__ unsigned short f2bf(float x) {
    unsigned u = __float_as_uint(x);
    u += 0x7FFF + ((u >> 16) & 1);   // RNE
    return (unsigned short)(u >> 16);
}
__device__ __forceinline__ float bf2f(unsigned short s) {
    return __uint_as_float(((unsigned)s) << 16);
}
__device__ __forceinline__ float fastrcp(float x) {
#if __has_builtin(__builtin_amdgcn_rcpf)
    return __builtin_amdgcn_rcpf(x);
#else
    return 1.0f / x;
#endif
}
__device__ __forceinline__ float sigmoid_(float x) {
    return fastrcp(1.0f + __expf(-x));
}
__device__ __forceinline__ float tanh_(float x) {
    return 2.0f * fastrcp(1.0f + __expf(-2.0f * x)) - 1.0f;
}

template<int IS_DEC>
__global__ __launch_bounds__(NTHREADS, 2) void gru_persistent(
    const float* __restrict__ X,       // [512][256][3]
    const float* __restrict__ W_hh,    // [768][256] gates r,z,n
    const float* __restrict__ W_ih,    // [768][3]
    const float* __restrict__ b_ih,    // [768]
    const float* __restrict__ b_hh,    // [768]
    const float* __restrict__ h_in,    // dec: [512][256] fp32; enc: null
    const float* __restrict__ noise,   // dec: [512][256]; enc: null
    float* __restrict__ h_out,         // enc: [512][256] fp32; dec: null
    unsigned short* __restrict__ Yout) // dec: [32][256][16][256] bf16
{
    __shared__ unsigned short shH[2 * HBUF];        // fragment-order bf16 h, dbuf
    __shared__ unsigned short shX[XSLOTS * XT];     // staged x: [t][c]{x0,x1,x2,1}

    const int tid  = threadIdx.x;
    const int g    = blockIdx.x;
    const int w    = tid >> 6;    // wave; owns hidden tiles {w, w+8}
    const int lane = tid & 63;
    const int c    = lane & 15;   // A row / B col (batch) / D col
    const int q    = lane >> 4;

    // ---- stage X into LDS (bf16, shift baked in; slot t = x for step t) ----
    for (int idx = tid; idx < NBATCH * XSLOTS; idx += NTHREADS) {
        int t = idx >> 4, cc = idx & 15;
        int ts = IS_DEC ? (t - 1) : t;
        float x0 = 0.0f, x1 = 0.0f, x2 = 0.0f;
        if (ts >= 0 && ts < T_LEN) {
            const float* xp = X + ((size_t)(g * NBATCH + cc) * T_LEN + ts) * 3;
            x0 = xp[0]; x1 = xp[1]; x2 = xp[2];
        }
        ushortx4 v = {f2bf(x0), f2bf(x1), f2bf(x2), (unsigned short)0x3F80};
        *(ushortx4*)&shX[t * XT + cc * 4] = v;
    }

    // ---- W_hh A-frags (all 3 gates) into registers, resident whole kernel --
    // A[m=c][k=q*8+j] -> lane holds W_hh[gbase+ht*16+c][kstep*32+q*8 .. +7]
    shortx8 Wf[2][3][8];   // [hti][r|z|n][k]
    #pragma unroll
    for (int hti = 0; hti < 2; ++hti) {
        int ht = w + hti * 8;
        #pragma unroll
        for (int gg = 0; gg < 3; ++gg) {
            int row = gg * 256 + ht * 16 + c;
            const float* wp = W_hh + (size_t)row * 256 + q * 8;
            #pragma unroll
            for (int k = 0; k < 8; ++k) {
                const f32x4* p = (const f32x4*)(wp + k * 32);
                f32x4 f0 = p[0];
                f32x4 f1 = p[1];
                shortx8 a;
                a[0] = (short)f2bf(f0[0]); a[1] = (short)f2bf(f0[1]);
                a[2] = (short)f2bf(f0[2]); a[3] = (short)f2bf(f0[3]);
                a[4] = (short)f2bf(f1[0]); a[5] = (short)f2bf(f1[1]);
                a[6] = (short)f2bf(f1[2]); a[7] = (short)f2bf(f1[3]);
                Wf[hti][gg][k] = a;
            }
        }
    }

    // ---- x/bias A-frags (q==0 lanes carry data; others MUST be zero) ----
#if HAVE_K16
    i16x4 ax[2][4];        // [hti][r, z, nh-bias, nx]; K=16: lane k=q*4+j
#else
    shortx8 ax[2][4];      // K=32 fallback: lane k=q*8+j, slots j>=4 zero
#endif
    #pragma unroll
    for (int hti = 0; hti < 2; ++hti) {
        int ht = w + hti * 8;
        int rr = ht * 16 + c;
        int rowr = rr, rowz = 256 + rr, rown = 512 + rr;
        short r0 = 0, r1 = 0, r2 = 0, r3 = 0, z0 = 0, z1 = 0, z2 = 0, z3 = 0;
        short n0 = 0, n1 = 0, n2 = 0, n3 = 0, nb = 0;
        if (q == 0) {
            r0 = (short)f2bf(W_ih[rowr * 3 + 0]);
            r1 = (short)f2bf(W_ih[rowr * 3 + 1]);
            r2 = (short)f2bf(W_ih[rowr * 3 + 2]);
            r3 = (short)f2bf(b_ih[rowr] + b_hh[rowr]);
            z0 = (short)f2bf(W_ih[rowz * 3 + 0]);
            z1 = (short)f2bf(W_ih[rowz * 3 + 1]);
            z2 = (short)f2bf(W_ih[rowz * 3 + 2]);
            z3 = (short)f2bf(b_ih[rowz] + b_hh[rowz]);
            n0 = (short)f2bf(W_ih[rown * 3 + 0]);
            n1 = (short)f2bf(W_ih[rown * 3 + 1]);
            n2 = (short)f2bf(W_ih[rown * 3 + 2]);
            n3 = (short)f2bf(b_ih[rown]);
            nb = (short)f2bf(b_hh[rown]);
        }
#if HAVE_K16
        ax[hti][0] = i16x4{r0, r1, r2, r3};
        ax[hti][1] = i16x4{z0, z1, z2, z3};
        ax[hti][2] = i16x4{0, 0, 0, nb};
        ax[hti][3] = i16x4{n0, n1, n2, n3};
#else
        ax[hti][0] = shortx8{r0, r1, r2, r3, 0, 0, 0, 0};
        ax[hti][1] = shortx8{z0, z1, z2, z3, 0, 0, 0, 0};
        ax[hti][2] = shortx8{0, 0, 0, nb, 0, 0, 0, 0};
        ax[hti][3] = shortx8{n0, n1, n2, n3, 0, 0, 0, 0};
#endif
    }

    // ---- epilogue offsets (fragment-order), loop-invariant ----
    // dim d0 = ht*16 + q*4 -> k'=ht>>1, qq=((ht&1)<<1)|(q>>1), j=(q&1)*4
    int woff[2];
    #pragma unroll
    for (int hti = 0; hti < 2; ++hti) {
        int ht = w + hti * 8;
        int kk = ht >> 1;
        int qq = ((ht & 1) << 1) | (q >> 1);
        woff[hti] = ((kk * 4 + qq) * 16 + c) * 8 + (q & 1) * 4;
    }

    // ---- init h0 bf16 into buffer 0 ----
    #pragma unroll
    for (int hti = 0; hti < 2; ++hti) {
        int ht = w + hti * 8;
        int dim0 = ht * 16 + q * 4;
        f32x4 hv = {0.0f, 0.0f, 0.0f, 0.0f};
        if (IS_DEC) {
            int b = g * NBATCH + c;
            f32x4 h0 = *(const f32x4*)(h_in + (size_t)b * HID + dim0);
            f32x4 nz = *(const f32x4*)(noise + (size_t)b * HID + dim0);
            hv = h0 + nz;
        }
        ushortx4 hb16 = {f2bf(hv[0]), f2bf(hv[1]), f2bf(hv[2]), f2bf(hv[3])};
        *(ushortx4*)&shH[woff[hti]] = hb16;
    }
    __syncthreads();

    const f32x4 zc = {0.0f, 0.0f, 0.0f, 0.0f};

    // ---- x-step for t=0 (C = inline 0 initializes the accumulators) ----
    f32x4 acc[2][4];  // [hti][r, z, nh, nx]
    {
#if HAVE_K16
        i16x4 bx = *(const i16x4*)&shX[c * 4];           // slot t=0
        #pragma unroll
        for (int hti = 0; hti < 2; ++hti)
            #pragma unroll
            for (int kk = 0; kk < 4; ++kk)
                acc[hti][kk] = MFMA_X(ax[hti][kk], bx, zc);
#else
        ushortx4 xv = *(const ushortx4*)&shX[c * 4];
        shortx8 bx = (q == 0)
            ? shortx8{(short)xv[0], (short)xv[1], (short)xv[2], (short)xv[3], 0, 0, 0, 0}
            : shortx8{0, 0, 0, 0, 0, 0, 0, 0};
        #pragma unroll
        for (int hti = 0; hti < 2; ++hti)
            #pragma unroll
            for (int kk = 0; kk < 4; ++kk)
                acc[hti][kk] = __builtin_amdgcn_mfma_f32_16x16x32_bf16(ax[hti][kk], bx, zc, 0, 0, 0);
#endif
    }

    const int bbase = q * 128 + c * 8;   // lane's B-frag base within a buffer

    // ---- recurrence ----
    for (int t = 0; t < T_LEN; ++t) {
        const unsigned short* hb = shH + (t & 1) * HBUF;
        unsigned short* hn = shH + ((t + 1) & 1) * HBUF;

        // h_t for this lane's own (c, d0) slots (carry path), issued early
        ushortx4 hu0 = *(const ushortx4*)(hb + woff[0]);
        ushortx4 hu1 = *(const ushortx4*)(hb + woff[1]);

        // main GEMM: 8 K-steps, B-frag addr = base + k*1024B (immediate)
        const unsigned short* brow = hb + bbase;
        #pragma unroll
        for (int k = 0; k < 8; ++k) {
            shortx8 bf = *(const shortx8*)(brow + k * 512);
            acc[0][0] = __builtin_amdgcn_mfma_f32_16x16x32_bf16(Wf[0][0][k], bf, acc[0][0], 0, 0, 0);
            acc[1][0] = __builtin_amdgcn_mfma_f32_16x16x32_bf16(Wf[1][0][k], bf, acc[1][0], 0, 0, 0);
            acc[0][1] = __builtin_amdgcn_mfma_f32_16x16x32_bf16(Wf[0][1][k], bf, acc[0][1], 0, 0, 0);
            acc[1][1] = __builtin_amdgcn_mfma_f32_16x16x32_bf16(Wf[1][1][k], bf, acc[1][1], 0, 0, 0);
            acc[0][2] = __builtin_amdgcn_mfma_f32_16x16x32_bf16(Wf[0][2][k], bf, acc[0][2], 0, 0, 0);
            acc[1][2] = __builtin_amdgcn_mfma_f32_16x16x32_bf16(Wf[1][2][k], bf, acc[1][2], 0, 0, 0);
        }

        // ---- epilogue: D[row=q*4+r][col=c]; h carried bf16 via LDS ----
        #pragma unroll
        for (int hti = 0; hti < 2; ++hti) {
            ushortx4 hu = hti ? hu1 : hu0;
            f32x4 ho;
            #pragma unroll
            for (int r = 0; r < 4; ++r) {
                float hv = bf2f(hu[r]);
                float rr = sigmoid_(acc[hti][0][r]);
                float zz = sigmoid_(acc[hti][1][r]);
                float nn = tanh_(acc[hti][3][r] + rr * acc[hti][2][r]);
                ho[r] = nn + zz * (hv - nn);
            }
            ushortx4 hb16 = {f2bf(ho[0]), f2bf(ho[1]), f2bf(ho[2]), f2bf(ho[3])};
            *(ushortx4*)(hn + woff[hti]) = hb16;
            if (IS_DEC) {
                int ht = w + hti * 8;
                unsigned short* yp = Yout +
                    (((size_t)g * T_LEN + t) * NBATCH + c) * HID + ht * 16 + q * 4;
                *(ushortx4*)yp = hb16;
            }
        }

        // ---- x-step for t+1 (independent of h -> fills barrier shadow) ----
        {
#if HAVE_K16
            i16x4 bx = *(const i16x4*)&shX[(t + 1) * XT + c * 4];
            #pragma unroll
            for (int hti = 0; hti < 2; ++hti)
                #pragma unroll
                for (int kk = 0; kk < 4; ++kk)
                    acc[hti][kk] = MFMA_X(ax[hti][kk], bx, zc);
#else
            ushortx4 xv = *(const ushortx4*)&shX[(t + 1) * XT + c * 4];
            shortx8 bx = (q == 0)
                ? shortx8{(short)xv[0], (short)xv[1], (short)xv[2], (short)xv[3], 0, 0, 0, 0}
                : shortx8{0, 0, 0, 0, 0, 0, 0, 0};
            #pragma unroll
            for (int hti = 0; hti < 2; ++hti)
                #pragma unroll
                for (int kk = 0; kk < 4; ++kk)
                    acc[hti][kk] = __builtin_amdgcn_mfma_f32_16x16x32_bf16(ax[hti][kk], bx, zc, 0, 0, 0);
#endif
        }
        __syncthreads();
    }

    if (!IS_DEC) {
        // final h sits in buffer 0 (T even); convert bf16 -> fp32 for decoder
        #pragma unroll
        for (int hti = 0; hti < 2; ++hti) {
            int ht = w + hti * 8;
            int dim0 = ht * 16 + q * 4;
            ushortx4 hu = *(const ushortx4*)(shH + woff[hti]);
            f32x4 o = {bf2f(hu[0]), bf2f(hu[1]), bf2f(hu[2]), bf2f(hu[3])};
            *(f32x4*)(h_out + (size_t)(g * NBATCH + c) * HID + dim0) = o;
        }
    }
}

// out[b][t][d] = sum_h Y[g][t][b16][h] * W_fc[d][h] + b_fc[d]
__global__ __launch_bounds__(256) void proj_kernel(
    const unsigned short* __restrict__ Y, const float* __restrict__ W_fc,
    const float* __restrict__ b_fc, float* __restrict__ out)
{
    int row = blockIdx.x * 256 + threadIdx.x;  // ((g*T + t)*16 + b16)
    int b16 = row & 15;
    int gt = row >> 4;
    int t = gt & (T_LEN - 1);
    int g = gt >> 8;
    const unsigned short* y = Y + (size_t)row * HID;
    float a0 = b_fc[0], a1 = b_fc[1], a2 = b_fc[2];
    #pragma unroll 4
    for (int k8 = 0; k8 < 32; ++k8) {
        ushortx8 v = *(const ushortx8*)(y + k8 * 8);
        #pragma unroll
        for (int j = 0; j < 8; ++j) {
            float f = bf2f(v[j]);
            int k = k8 * 8 + j;
            a0 += f * W_fc[k];          // uniform -> scalar loads
            a1 += f * W_fc[256 + k];
            a2 += f * W_fc[512 + k];
        }
    }
    int batch = g * NBATCH + b16;
    float* o = out + ((size_t)batch * T_LEN + t) * 3;
    o[0] = a0; o[1] = a1; o[2] = a2;
}

extern "C" void kernel_launch(void* const* d_in, const int* in_sizes, int n_in,
                              void* d_out, int out_size, void* d_ws, size_t ws_size,
                              hipStream_t stream)
{
    const float* X_p      = (const float*)d_in[0];
    const float* X_f      = (const float*)d_in[1];
    const float* noise    = (const float*)d_in[2];
    const float* W_ih_enc = (const float*)d_in[3];
    const float* W_hh_enc = (const float*)d_in[4];
    const float* b_ih_enc = (const float*)d_in[5];
    const float* b_hh_enc = (const float*)d_in[6];
    const float* W_ih_dec = (const float*)d_in[7];
    const float* W_hh_dec = (const float*)d_in[8];
    const float* b_ih_dec = (const float*)d_in[9];
    const float* b_hh_dec = (const float*)d_in[10];
    const float* W_fc     = (const float*)d_in[11];
    const float* b_fc     = (const float*)d_in[12];

    // ws: [0, 512KB) fp32 encoder final h; then 16MB bf16 decoder outputs
    float* h_enc = (float*)d_ws;
    unsigned short* Yws = (unsigned short*)((char*)d_ws + (size_t)B_TOT * HID * 4);

    hipLaunchKernelGGL((gru_persistent<0>), dim3(NBLK), dim3(NTHREADS), 0, stream,
        X_p, W_hh_enc, W_ih_enc, b_ih_enc, b_hh_enc,
        (const float*)nullptr, (const float*)nullptr, h_enc,
        (unsigned short*)nullptr);

    hipLaunchKernelGGL((gru_persistent<1>), dim3(NBLK), dim3(NTHREADS), 0, stream,
        X_f, W_hh_dec, W_ih_dec, b_ih_dec, b_hh_dec,
        h_enc, noise, (float*)nullptr, Yws);

    hipLaunchKernelGGL(proj_kernel, dim3((B_TOT * T_LEN) / 256), dim3(256), 0, stream,
        Yws, W_fc, b_fc, (float*)d_out);
}

// Round 6
// 900.641 us; speedup vs baseline: 1.1237x; 1.1237x over previous
//
#include <hip/hip_runtime.h>

// NetG: seq2seq GRU (enc GRU -> +noise -> dec GRU -> FC head)
// B=512, T=256, H=256, D=3.
//
// Persistent-RNN: 32 blocks x 512 threads (8 waves, 2/SIMD -> 256 reg cap).
// Each block owns 16 batch rows for all 256 steps.
//
// R5 post-mortem: all-3-gates-in-regs (192) spilled (WRITE_SIZE 87 MB of
// scratch). Register floor for full residency is 192 + acc + temps > 256.
// R6: gates z,n resident (128 regs). Gate r is STREAMED, split across the
// two idle/underused pipes so it overlaps the MFMA floor (~1790 cyc/step):
//   k=0..3 from LDS  (64 KB/step; ds pipe ~= h reads 64 KB + this = 1540 cyc)
//   k=4..7 from GLOBAL L2 as pre-packed frags (64 KB/step on the idle VMEM
//   pipe; loop-invariant addresses issued right after the barrier).
// A prep kernel packs the global half into per-lane fragment layout in ws.
//
// h LDS layout in FRAGMENT ORDER: element h[c][32k+q*8+j] at
// ((k*4+q)*16+c)*16B + j*2B -> B-frag read = lane base + k*1024B immediate,
// <=2-way bank aliasing (free). h carried bf16 (R5: absmax unchanged).
// X staged once in LDS [t][c] (shift baked in); x-projection + biases ride
// a K=16 MFMA with C = inline 0 (also initializes accumulators), issued in
// the barrier shadow for step t+1.

#define B_TOT 512
#define T_LEN 256
#define HID 256
#define NBATCH 16
#define NTHREADS 512
#define NBLK 32

#define XT 64                  // shorts per t-slot of staged X (16 c x 4)
#define XSLOTS (T_LEN + 1)     // slot t = x for step t; +1 pad slot
#define HBUF (NBATCH * HID)    // 4096 shorts per h buffer

// dynamic LDS partition (units: shorts)
#define WR_OFF 0               // gate-r k=0..3 frags: 16*4*64*8 = 32768
#define H_OFF  32768           // 2 x 4096
#define X_OFF  40960           // 257 x 64 = 16448
#define SMEM_SHORTS 57408
#define SMEM_BYTES  (SMEM_SHORTS * 2)   // 114816 B <= 160 KiB

typedef __attribute__((ext_vector_type(4))) float f32x4;
typedef __attribute__((ext_vector_type(8))) short shortx8;
typedef __attribute__((ext_vector_type(4))) short i16x4;
typedef __attribute__((ext_vector_type(4))) unsigned short ushortx4;
typedef __attribute__((ext_vector_type(8))) unsigned short ushortx8;

#if __has_builtin(__builtin_amdgcn_mfma_f32_16x16x16_bf16)
#define HAVE_K16 1
#define MFMA_X(A, B, C) __builtin_amdgcn_mfma_f32_16x16x16_bf16((A), (B), (C), 0, 0, 0)
#elif __has_builtin(__builtin_amdgcn_mfma_f32_16x16x16bf16_1k)
#define HAVE_K16 1
#define MFMA_X(A, B, C) __builtin_amdgcn_mfma_f32_16x16x16bf16_1k((A), (B), (C), 0, 0, 0)
#else
#define HAVE_K16 0
#endif

__device__ __forceinline__ unsigned short f2bf(float x) {
    unsigned u = __float_as_uint(x);
    u += 0x7FFF + ((u >> 16) & 1);   // RNE
    return (unsigned short)(u >> 16);
}
__device__ __forceinline__ float bf2f(unsigned short s) {
    return __uint_as_float(((unsigned)s) << 16);
}
__device__ __forceinline__ float fastrcp(float x) {
#if __has_builtin(__builtin_amdgcn_rcpf)
    return __builtin_amdgcn_rcpf(x);
#else
    return 1.0f / x;
#endif
}
__device__ __forceinline__ float sigmoid_(float x) {
    return fastrcp(1.0f + __expf(-x));
}
__device__ __forceinline__ float tanh_(float x) {
    return 2.0f * fastrcp(1.0f + __expf(-2.0f * x)) - 1.0f;
}

// Pack gate-r (rows 0..255 of W_hh), K-half k=4..7, into per-lane fragment
// layout: dst[((ht*4+kk)*64+lane)*8 + j] = bf16(W[ht*16+(lane&15)][(kk+4)*32+(lane>>4)*8+j])
__global__ __launch_bounds__(256) void prep_wr(
    const float* __restrict__ Whh_enc, const float* __restrict__ Whh_dec,
    unsigned short* __restrict__ wr_enc, unsigned short* __restrict__ wr_dec)
{
    int idx = blockIdx.x * 256 + threadIdx.x;    // 0..8191
    int gru = idx >> 12;
    int rem = idx & 4095;                        // (ht*4+kk)*64 + lane
    int lane = rem & 63;
    int kk = (rem >> 6) & 3;
    int ht = rem >> 8;
    const float* W = gru ? Whh_dec : Whh_enc;
    unsigned short* dst = gru ? wr_dec : wr_enc;
    int row = ht * 16 + (lane & 15);
    int col = (kk + 4) * 32 + (lane >> 4) * 8;
    const float* src = W + (size_t)row * 256 + col;
    ushortx8 v;
    #pragma unroll
    for (int j = 0; j < 8; ++j) v[j] = f2bf(src[j]);
    *(ushortx8*)(dst + (size_t)rem * 8) = v;
}

template<int IS_DEC>
__global__ __launch_bounds__(NTHREADS, 2) void gru_persistent(
    const float* __restrict__ X,       // [512][256][3]
    const float* __restrict__ W_hh,    // [768][256] gates r,z,n
    const float* __restrict__ W_ih,    // [768][3]
    const float* __restrict__ b_ih,    // [768]
    const float* __restrict__ b_hh,    // [768]
    const unsigned short* __restrict__ Wr4, // gate-r k=4..7 frags (prep_wr)
    const float* __restrict__ h_in,    // dec: [512][256] fp32; enc: null
    const float* __restrict__ noise,   // dec: [512][256]; enc: null
    float* __restrict__ h_out,         // enc: [512][256] fp32; dec: null
    unsigned short* __restrict__ Yout) // dec: [32][256][16][256] bf16
{
    extern __shared__ unsigned short smem[];
    unsigned short* shWr = smem + WR_OFF;
    unsigned short* shH  = smem + H_OFF;
    unsigned short* shX  = smem + X_OFF;

    const int tid  = threadIdx.x;
    const int g    = blockIdx.x;
    const int w    = tid >> 6;    // wave; owns hidden tiles {w, w+8}
    const int lane = tid & 63;
    const int c    = lane & 15;   // A row / B col (batch) / D col
    const int q    = lane >> 4;

    // ---- stage X into LDS (bf16, shift baked in; slot t = x for step t) ----
    for (int idx = tid; idx < NBATCH * XSLOTS; idx += NTHREADS) {
        int t = idx >> 4, cc = idx & 15;
        int ts = IS_DEC ? (t - 1) : t;
        float x0 = 0.0f, x1 = 0.0f, x2 = 0.0f;
        if (ts >= 0 && ts < T_LEN) {
            const float* xp = X + ((size_t)(g * NBATCH + cc) * T_LEN + ts) * 3;
            x0 = xp[0]; x1 = xp[1]; x2 = xp[2];
        }
        ushortx4 v = {f2bf(x0), f2bf(x1), f2bf(x2), (unsigned short)0x3F80};
        *(ushortx4*)&shX[t * XT + cc * 4] = v;
    }

    // ---- gate-r k=0..3 frags -> LDS (each wave stages its 2 tiles) ----
    #pragma unroll
    for (int hti = 0; hti < 2; ++hti) {
        int ht = w + hti * 8;
        int row = ht * 16 + c;                      // gate r
        const float* wp = W_hh + (size_t)row * 256 + q * 8;
        #pragma unroll
        for (int k = 0; k < 4; ++k) {
            const f32x4* p = (const f32x4*)(wp + k * 32);
            f32x4 f0 = p[0];
            f32x4 f1 = p[1];
            shortx8 a;
            a[0] = (short)f2bf(f0[0]); a[1] = (short)f2bf(f0[1]);
            a[2] = (short)f2bf(f0[2]); a[3] = (short)f2bf(f0[3]);
            a[4] = (short)f2bf(f1[0]); a[5] = (short)f2bf(f1[1]);
            a[6] = (short)f2bf(f1[2]); a[7] = (short)f2bf(f1[3]);
            *(shortx8*)&shWr[((ht * 4 + k) * 64 + lane) * 8] = a;
        }
    }

    // ---- gates z,n A-frags into registers (128 regs, resident) ----
    shortx8 Wf[2][2][8];   // [hti][z|n][k]
    #pragma unroll
    for (int hti = 0; hti < 2; ++hti) {
        int ht = w + hti * 8;
        #pragma unroll
        for (int gg = 0; gg < 2; ++gg) {
            int row = (gg + 1) * 256 + ht * 16 + c;
            const float* wp = W_hh + (size_t)row * 256 + q * 8;
            #pragma unroll
            for (int k = 0; k < 8; ++k) {
                const f32x4* p = (const f32x4*)(wp + k * 32);
                f32x4 f0 = p[0];
                f32x4 f1 = p[1];
                shortx8 a;
                a[0] = (short)f2bf(f0[0]); a[1] = (short)f2bf(f0[1]);
                a[2] = (short)f2bf(f0[2]); a[3] = (short)f2bf(f0[3]);
                a[4] = (short)f2bf(f1[0]); a[5] = (short)f2bf(f1[1]);
                a[6] = (short)f2bf(f1[2]); a[7] = (short)f2bf(f1[3]);
                Wf[hti][gg][k] = a;
            }
        }
    }

    // ---- x/bias A-frags (q==0 lanes carry data; others MUST be zero) ----
#if HAVE_K16
    i16x4 ax[2][4];        // [hti][r, z, nh-bias, nx]; K=16: lane k=q*4+j
#else
    shortx8 ax[2][4];      // K=32 fallback
#endif
    #pragma unroll
    for (int hti = 0; hti < 2; ++hti) {
        int ht = w + hti * 8;
        int rr = ht * 16 + c;
        int rowr = rr, rowz = 256 + rr, rown = 512 + rr;
        short r0 = 0, r1 = 0, r2 = 0, r3 = 0, z0 = 0, z1 = 0, z2 = 0, z3 = 0;
        short n0 = 0, n1 = 0, n2 = 0, n3 = 0, nb = 0;
        if (q == 0) {
            r0 = (short)f2bf(W_ih[rowr * 3 + 0]);
            r1 = (short)f2bf(W_ih[rowr * 3 + 1]);
            r2 = (short)f2bf(W_ih[rowr * 3 + 2]);
            r3 = (short)f2bf(b_ih[rowr] + b_hh[rowr]);
            z0 = (short)f2bf(W_ih[rowz * 3 + 0]);
            z1 = (short)f2bf(W_ih[rowz * 3 + 1]);
            z2 = (short)f2bf(W_ih[rowz * 3 + 2]);
            z3 = (short)f2bf(b_ih[rowz] + b_hh[rowz]);
            n0 = (short)f2bf(W_ih[rown * 3 + 0]);
            n1 = (short)f2bf(W_ih[rown * 3 + 1]);
            n2 = (short)f2bf(W_ih[rown * 3 + 2]);
            n3 = (short)f2bf(b_ih[rown]);
            nb = (short)f2bf(b_hh[rown]);
        }
#if HAVE_K16
        ax[hti][0] = i16x4{r0, r1, r2, r3};
        ax[hti][1] = i16x4{z0, z1, z2, z3};
        ax[hti][2] = i16x4{0, 0, 0, nb};
        ax[hti][3] = i16x4{n0, n1, n2, n3};
#else
        ax[hti][0] = shortx8{r0, r1, r2, r3, 0, 0, 0, 0};
        ax[hti][1] = shortx8{z0, z1, z2, z3, 0, 0, 0, 0};
        ax[hti][2] = shortx8{0, 0, 0, nb, 0, 0, 0, 0};
        ax[hti][3] = shortx8{n0, n1, n2, n3, 0, 0, 0, 0};
#endif
    }

    // ---- epilogue offsets (fragment-order), loop-invariant ----
    int woff[2];
    #pragma unroll
    for (int hti = 0; hti < 2; ++hti) {
        int ht = w + hti * 8;
        int kk = ht >> 1;
        int qq = ((ht & 1) << 1) | (q >> 1);
        woff[hti] = ((kk * 4 + qq) * 16 + c) * 8 + (q & 1) * 4;
    }

    // ---- init h0 bf16 into buffer 0 ----
    #pragma unroll
    for (int hti = 0; hti < 2; ++hti) {
        int ht = w + hti * 8;
        int dim0 = ht * 16 + q * 4;
        f32x4 hv = {0.0f, 0.0f, 0.0f, 0.0f};
        if (IS_DEC) {
            int b = g * NBATCH + c;
            f32x4 h0 = *(const f32x4*)(h_in + (size_t)b * HID + dim0);
            f32x4 nz = *(const f32x4*)(noise + (size_t)b * HID + dim0);
            hv = h0 + nz;
        }
        ushortx4 hb16 = {f2bf(hv[0]), f2bf(hv[1]), f2bf(hv[2]), f2bf(hv[3])};
        *(ushortx4*)&shH[woff[hti]] = hb16;
    }
    __syncthreads();

    const f32x4 zc = {0.0f, 0.0f, 0.0f, 0.0f};

    // ---- x-step for t=0 (C = inline 0 initializes the accumulators) ----
    f32x4 acc[2][4];  // [hti][r, z, nh, nx]
    {
#if HAVE_K16
        i16x4 bx = *(const i16x4*)&shX[c * 4];
        #pragma unroll
        for (int hti = 0; hti < 2; ++hti)
            #pragma unroll
            for (int kk = 0; kk < 4; ++kk)
                acc[hti][kk] = MFMA_X(ax[hti][kk], bx, zc);
#else
        ushortx4 xv = *(const ushortx4*)&shX[c * 4];
        shortx8 bx = (q == 0)
            ? shortx8{(short)xv[0], (short)xv[1], (short)xv[2], (short)xv[3], 0, 0, 0, 0}
            : shortx8{0, 0, 0, 0, 0, 0, 0, 0};
        #pragma unroll
        for (int hti = 0; hti < 2; ++hti)
            #pragma unroll
            for (int kk = 0; kk < 4; ++kk)
                acc[hti][kk] = __builtin_amdgcn_mfma_f32_16x16x32_bf16(ax[hti][kk], bx, zc, 0, 0, 0);
#endif
    }

    const int bbase = q * 128 + c * 8;              // lane's B-frag base
    const unsigned short* ab0 = shWr + ((size_t)(w * 4) * 64 + lane) * 8;
    const unsigned short* ab1 = shWr + ((size_t)((w + 8) * 4) * 64 + lane) * 8;
    const unsigned short* gb0 = Wr4 + ((size_t)(w * 4) * 64 + lane) * 8;
    const unsigned short* gb1 = Wr4 + ((size_t)((w + 8) * 4) * 64 + lane) * 8;

    // ---- recurrence ----
    for (int t = 0; t < T_LEN; ++t) {
        const unsigned short* hb = shH + (t & 1) * HBUF;
        unsigned short* hn = shH + ((t + 1) & 1) * HBUF;

        // gate-r k=4..7 from global (loop-invariant addrs; L2-resident;
        // issued first, consumed half a step later on the idle VMEM pipe)
        shortx8 gr0[4], gr1[4];
        #pragma unroll
        for (int kk = 0; kk < 4; ++kk) {
            gr0[kk] = *(const shortx8*)(gb0 + kk * 512);
            gr1[kk] = *(const shortx8*)(gb1 + kk * 512);
        }

        // h_t carry slots (b64 ds reads, needed only at epilogue)
        ushortx4 hu0 = *(const ushortx4*)(hb + woff[0]);
        ushortx4 hu1 = *(const ushortx4*)(hb + woff[1]);

        const unsigned short* brow = hb + bbase;

        // k=0..3: gate-r from LDS
        #pragma unroll
        for (int k = 0; k < 4; ++k) {
            shortx8 bf  = *(const shortx8*)(brow + k * 512);
            shortx8 ar0 = *(const shortx8*)(ab0 + k * 512);
            shortx8 ar1 = *(const shortx8*)(ab1 + k * 512);
            acc[0][0] = __builtin_amdgcn_mfma_f32_16x16x32_bf16(ar0,         bf, acc[0][0], 0, 0, 0);
            acc[1][0] = __builtin_amdgcn_mfma_f32_16x16x32_bf16(ar1,         bf, acc[1][0], 0, 0, 0);
            acc[0][1] = __builtin_amdgcn_mfma_f32_16x16x32_bf16(Wf[0][0][k], bf, acc[0][1], 0, 0, 0);
            acc[1][1] = __builtin_amdgcn_mfma_f32_16x16x32_bf16(Wf[1][0][k], bf, acc[1][1], 0, 0, 0);
            acc[0][2] = __builtin_amdgcn_mfma_f32_16x16x32_bf16(Wf[0][1][k], bf, acc[0][2], 0, 0, 0);
            acc[1][2] = __builtin_amdgcn_mfma_f32_16x16x32_bf16(Wf[1][1][k], bf, acc[1][2], 0, 0, 0);
        }
        // k=4..7: gate-r from the global prefetch
        #pragma unroll
        for (int k = 4; k < 8; ++k) {
            shortx8 bf = *(const shortx8*)(brow + k * 512);
            acc[0][0] = __builtin_amdgcn_mfma_f32_16x16x32_bf16(gr0[k - 4],  bf, acc[0][0], 0, 0, 0);
            acc[1][0] = __builtin_amdgcn_mfma_f32_16x16x32_bf16(gr1[k - 4],  bf, acc[1][0], 0, 0, 0);
            acc[0][1] = __builtin_amdgcn_mfma_f32_16x16x32_bf16(Wf[0][0][k], bf, acc[0][1], 0, 0, 0);
            acc[1][1] = __builtin_amdgcn_mfma_f32_16x16x32_bf16(Wf[1][0][k], bf, acc[1][1], 0, 0, 0);
            acc[0][2] = __builtin_amdgcn_mfma_f32_16x16x32_bf16(Wf[0][1][k], bf, acc[0][2], 0, 0, 0);
            acc[1][2] = __builtin_amdgcn_mfma_f32_16x16x32_bf16(Wf[1][1][k], bf, acc[1][2], 0, 0, 0);
        }

        // ---- epilogue: D[row=q*4+r][col=c]; h carried bf16 via LDS ----
        #pragma unroll
        for (int hti = 0; hti < 2; ++hti) {
            ushortx4 hu = hti ? hu1 : hu0;
            f32x4 ho;
            #pragma unroll
            for (int r = 0; r < 4; ++r) {
                float hv = bf2f(hu[r]);
                float rr = sigmoid_(acc[hti][0][r]);
                float zz = sigmoid_(acc[hti][1][r]);
                float nn = tanh_(acc[hti][3][r] + rr * acc[hti][2][r]);
                ho[r] = nn + zz * (hv - nn);
            }
            ushortx4 hb16 = {f2bf(ho[0]), f2bf(ho[1]), f2bf(ho[2]), f2bf(ho[3])};
            *(ushortx4*)(hn + woff[hti]) = hb16;
            if (IS_DEC) {
                int ht = w + hti * 8;
                unsigned short* yp = Yout +
                    (((size_t)g * T_LEN + t) * NBATCH + c) * HID + ht * 16 + q * 4;
                *(ushortx4*)yp = hb16;
            }
        }

        // ---- x-step for t+1 (independent of h -> fills barrier shadow) ----
        {
#if HAVE_K16
            i16x4 bx = *(const i16x4*)&shX[(t + 1) * XT + c * 4];
            #pragma unroll
            for (int hti = 0; hti < 2; ++hti)
                #pragma unroll
                for (int kk = 0; kk < 4; ++kk)
                    acc[hti][kk] = MFMA_X(ax[hti][kk], bx, zc);
#else
            ushortx4 xv = *(const ushortx4*)&shX[(t + 1) * XT + c * 4];
            shortx8 bx = (q == 0)
                ? shortx8{(short)xv[0], (short)xv[1], (short)xv[2], (short)xv[3], 0, 0, 0, 0}
                : shortx8{0, 0, 0, 0, 0, 0, 0, 0};
            #pragma unroll
            for (int hti = 0; hti < 2; ++hti)
                #pragma unroll
                for (int kk = 0; kk < 4; ++kk)
                    acc[hti][kk] = __builtin_amdgcn_mfma_f32_16x16x32_bf16(ax[hti][kk], bx, zc, 0, 0, 0);
#endif
        }
        __syncthreads();
    }

    if (!IS_DEC) {
        // final h in buffer 0 (T even); bf16 -> fp32 for the decoder
        #pragma unroll
        for (int hti = 0; hti < 2; ++hti) {
            int ht = w + hti * 8;
            int dim0 = ht * 16 + q * 4;
            ushortx4 hu = *(const ushortx4*)(shH + woff[hti]);
            f32x4 o = {bf2f(hu[0]), bf2f(hu[1]), bf2f(hu[2]), bf2f(hu[3])};
            *(f32x4*)(h_out + (size_t)(g * NBATCH + c) * HID + dim0) = o;
        }
    }
}

// out[b][t][d] = sum_h Y[g][t][b16][h] * W_fc[d][h] + b_fc[d]
__global__ __launch_bounds__(256) void proj_kernel(
    const unsigned short* __restrict__ Y, const float* __restrict__ W_fc,
    const float* __restrict__ b_fc, float* __restrict__ out)
{
    int row = blockIdx.x * 256 + threadIdx.x;  // ((g*T + t)*16 + b16)
    int b16 = row & 15;
    int gt = row >> 4;
    int t = gt & (T_LEN - 1);
    int g = gt >> 8;
    const unsigned short* y = Y + (size_t)row * HID;
    float a0 = b_fc[0], a1 = b_fc[1], a2 = b_fc[2];
    #pragma unroll 4
    for (int k8 = 0; k8 < 32; ++k8) {
        ushortx8 v = *(const ushortx8*)(y + k8 * 8);
        #pragma unroll
        for (int j = 0; j < 8; ++j) {
            float f = bf2f(v[j]);
            int k = k8 * 8 + j;
            a0 += f * W_fc[k];          // uniform -> scalar loads
            a1 += f * W_fc[256 + k];
            a2 += f * W_fc[512 + k];
        }
    }
    int batch = g * NBATCH + b16;
    float* o = out + ((size_t)batch * T_LEN + t) * 3;
    o[0] = a0; o[1] = a1; o[2] = a2;
}

extern "C" void kernel_launch(void* const* d_in, const int* in_sizes, int n_in,
                              void* d_out, int out_size, void* d_ws, size_t ws_size,
                              hipStream_t stream)
{
    const float* X_p      = (const float*)d_in[0];
    const float* X_f      = (const float*)d_in[1];
    const float* noise    = (const float*)d_in[2];
    const float* W_ih_enc = (const float*)d_in[3];
    const float* W_hh_enc = (const float*)d_in[4];
    const float* b_ih_enc = (const float*)d_in[5];
    const float* b_hh_enc = (const float*)d_in[6];
    const float* W_ih_dec = (const float*)d_in[7];
    const float* W_hh_dec = (const float*)d_in[8];
    const float* b_ih_dec = (const float*)d_in[9];
    const float* b_hh_dec = (const float*)d_in[10];
    const float* W_fc     = (const float*)d_in[11];
    const float* b_fc     = (const float*)d_in[12];

    // allow >64 KiB dynamic LDS (idempotent; host-side, graph-capture safe)
    (void)hipFuncSetAttribute((const void*)&gru_persistent<0>,
                              hipFuncAttributeMaxDynamicSharedMemorySize, SMEM_BYTES);
    (void)hipFuncSetAttribute((const void*)&gru_persistent<1>,
                              hipFuncAttributeMaxDynamicSharedMemorySize, SMEM_BYTES);

    // ws: [0,512K) h_enc fp32 | [512K,576K) Wr_enc | [576K,640K) Wr_dec |
    //     [640K, +67.1MB) decoder Y bf16
    float* h_enc = (float*)d_ws;
    unsigned short* wr_enc = (unsigned short*)((char*)d_ws + (512u << 10));
    unsigned short* wr_dec = (unsigned short*)((char*)d_ws + (576u << 10));
    unsigned short* Yws    = (unsigned short*)((char*)d_ws + (640u << 10));

    hipLaunchKernelGGL(prep_wr, dim3(32), dim3(256), 0, stream,
        W_hh_enc, W_hh_dec, wr_enc, wr_dec);

    hipLaunchKernelGGL((gru_persistent<0>), dim3(NBLK), dim3(NTHREADS), SMEM_BYTES, stream,
        X_p, W_hh_enc, W_ih_enc, b_ih_enc, b_hh_enc, wr_enc,
        (const float*)nullptr, (const float*)nullptr, h_enc,
        (unsigned short*)nullptr);

    hipLaunchKernelGGL((gru_persistent<1>), dim3(NBLK), dim3(NTHREADS), SMEM_BYTES, stream,
        X_f, W_hh_dec, W_ih_dec, b_ih_dec, b_hh_dec, wr_dec,
        h_enc, noise, (float*)nullptr, Yws);

    hipLaunchKernelGGL(proj_kernel, dim3((B_TOT * T_LEN) / 256), dim3(256), 0, stream,
        Yws, W_fc, b_fc, (float*)d_out);
}